// Round 6
// baseline (293.734 us; speedup 1.0000x reference)
//
#include <hip/hip_runtime.h>
#include <hip/hip_bf16.h>

#define BB 16
#define CIN 256
#define COUT 256
#define HH 64
#define WW 64
#define SDIM 512

typedef __attribute__((ext_vector_type(8))) short bf16x8;
typedef __attribute__((ext_vector_type(4))) float f32x4;

static __device__ __forceinline__ short f2bf(float v) {
    __hip_bfloat16 h = __float2bfloat16(v);
    return *reinterpret_cast<short*>(&h);
}

// ---------------- kernel 1: wT bf16 transform + wsq in one pass -----------
__global__ void wprep_kernel(const float* __restrict__ w,
                             __hip_bfloat16* __restrict__ wT,
                             float* __restrict__ wsq) {
    int co = blockIdx.x;   // 256
    int ci = threadIdx.x;  // 256
    const float* wp = w + ((size_t)co * CIN + ci) * 9;
    float acc = 0.f;
#pragma unroll
    for (int k = 0; k < 9; ++k) {
        float v = wp[k];
        acc += v * v;
        wT[((size_t)co * 9 + k) * CIN + ci] = __float2bfloat16(v);
    }
    wsq[co * CIN + ci] = acc;
}

// ------ kernel 2: xmod = bf16(x*s) with style-projection FUSED ------------
// Each block (y4, g, b) computes its own 8-ci style slice (8 x 512 dot,
// trivial) -> removes the style_proj dispatch + its stream gap. Block 0 of
// each (g,b) also publishes s to global for conv's inline demod.
// layout xm[b][g=ci/8][y][x][ci%8].
__global__ void xmod_kernel(const float* __restrict__ x,
                            const float* __restrict__ style,
                            const float* __restrict__ style_w,
                            const float* __restrict__ style_b,
                            float* __restrict__ s,
                            __hip_bfloat16* __restrict__ xm) {
    __shared__ float sls[8];
    int t = threadIdx.x;
    int g = blockIdx.y, b = blockIdx.z;
    {
        int c = t >> 5, p = t & 31;  // 8 ci x 32-thread dot groups
        float acc = 0.f;
        const float* st = style + b * SDIM + p * 16;
        const float* W  = style_w + (size_t)(p * 16) * CIN + g * 8 + c;
#pragma unroll
        for (int i = 0; i < 16; ++i) acc += st[i] * W[(size_t)i * CIN];
#pragma unroll
        for (int off = 16; off; off >>= 1) acc += __shfl_down(acc, off, 32);
        if (p == 0) {
            float v = acc + style_b[g * 8 + c];
            sls[c] = v;
            if (blockIdx.x == 0) s[b * CIN + g * 8 + c] = v;
        }
    }
    __syncthreads();
    int px = t & 63;
    int y  = blockIdx.x * 4 + (t >> 6);
    const float* xp = x + (((size_t)(b * CIN + g * 8)) * HH + y) * WW + px;
    bf16x8 v;
#pragma unroll
    for (int c = 0; c < 8; ++c) v[c] = f2bf(xp[(size_t)c * (HH * WW)] * sls[c]);
    *(bf16x8*)(xm + ((((size_t)(b * 32 + g)) * HH + y) * WW + px) * 8) = v;
}

// ---- async global->LDS DMA for one 32-ci chunk: 5 insts/wave, ~0 VALU ----
// 40 (y,g) units over 8 waves; LDS dest = uniform base (+HW lane*16B).
__device__ __forceinline__ void stage_dma8(__hip_bfloat16* xs,
                                           const __hip_bfloat16* __restrict__ xm,
                                           int b, int cc, int Y0, int lane,
                                           int wave) {
#pragma unroll
    for (int i = 0; i < 5; ++i) {
        int u = wave * 5 + i;          // u = y*4 + g, y in [0,10)
        int y = u >> 2, g = u & 3;
        int yr = Y0 - 1 + y;
        if ((unsigned)yr < (unsigned)HH) {   // wave-uniform branch
            __hip_bfloat16* dst = xs + (u * 66 + 1) * 8;  // cols 1..64
            const __hip_bfloat16* src =
                xm + ((((size_t)(b * 32 + cc * 4 + g)) * HH + yr) * WW + lane) * 8;
            __builtin_amdgcn_global_load_lds(
                (const __attribute__((address_space(1))) void*)src,
                (__attribute__((address_space(3))) void*)dst, 16, 0, 0);
        }
    }
}

// ---- kernel 3: fused modulated conv — 2 BLOCKS/CU, 16 waves/CU -----------
// R5 post-mortem: 8 lockstep waves/CU -> pipes ran SERIALLY (MFMA 89k +
// LDS 74k + VALU 28k ~= measured 233k cyc). Fix = co-residency:
//   wave = 32co x 2 rows  -> acc 64 AGPR (was 128)
//   dx-outer af window    -> af 24 VGPR (was 72); same load/ds_read counts
//   single 42KB LDS buffer, block tile co64 x y8, grid 512 = 2/CU exactly
//   launch_bounds(512,4)  -> 128-reg budget, 4 waves/SIMD
// Cross-block overlap hides the single-buffer stage drain (R3's exposed
// stall) and de-lockstops the pipes. REVERT CRITERION: WRITE_SIZE >> 100MB
// means the 128-reg budget spilled (R2 failure mode) -> go back to R5.
__global__ __launch_bounds__(512, 4) void conv_mfma_kernel(
    const __hip_bfloat16* __restrict__ xm, const __hip_bfloat16* __restrict__ wT,
    const float* __restrict__ wsq, const float* __restrict__ s,
    float* __restrict__ out) {
    __shared__ __hip_bfloat16 xs[40 * 66 * 8];  // 42240 B
    __shared__ float dls[64];

    int tid  = threadIdx.x;
    int lane = tid & 63;
    int wave = tid >> 6;   // 0..7
    int wco  = wave & 1;   // co half (32 co)
    int rq   = wave >> 1;  // row pair: output rows rq*2, rq*2+1
    int n    = lane & 15;
    int quad = lane >> 4;

    int Y0  = blockIdx.x * 8;   // 8 y-tiles x 8 output rows
    int co0 = blockIdx.y * 64;  // 4 co blocks
    int b   = blockIdx.z;

    const bf16x8 zv = (bf16x8){0, 0, 0, 0, 0, 0, 0, 0};
    // zero halo cols (0,65) of all 40 units — ONCE (DMA never touches them)
    if (tid < 80) {
        int u = tid >> 1, col = (tid & 1) * 65;
        *(bf16x8*)(&xs[(u * 66 + col) * 8]) = zv;
    }
    // zero out-of-range rows — ONCE; DMA skips them every cc
    if (Y0 == 0 && tid < 264)
        *(bf16x8*)(&xs[tid * 8]) = zv;                    // units 0..3
    if (Y0 + 8 == HH && tid < 264)
        *(bf16x8*)(&xs[(36 * 66 + tid) * 8]) = zv;        // units 36..39

    // first chunk DMA ASAP; demod VALU below overlaps its latency
    stage_dma8(xs, xm, b, 0, Y0, lane, wave);

    // inline demod for this block's 64 co (8 threads per co)
    {
        int colco = tid >> 3, part = tid & 7;
        float dacc = 0.f;
        const float* wrow = wsq + (size_t)(co0 + colco) * CIN + part * 32;
        const float* srow = s + b * CIN + part * 32;
#pragma unroll 8
        for (int i = 0; i < 32; ++i) {
            float sv = srow[i];
            dacc += wrow[i] * sv * sv;
        }
        dacc += __shfl_down(dacc, 4, 64);
        dacc += __shfl_down(dacc, 2, 64);
        dacc += __shfl_down(dacc, 1, 64);
        if (part == 0)
            dls[colco] = rsqrtf(dacc * (1.0f / (CIN * 9)) + 1e-8f);
    }

    // A base: wT[co][k][ci]; this wave's A rows: co0 + wco*32 + m*16 + n
    const __hip_bfloat16* wb =
        wT + ((size_t)(co0 + wco * 32 + n) * 9) * CIN + quad * 8;

    f32x4 acc[2][2][4];  // [wr][m][j] = 64 accumulator regs
#pragma unroll
    for (int wr = 0; wr < 2; ++wr)
#pragma unroll
        for (int m = 0; m < 2; ++m)
#pragma unroll
            for (int j = 0; j < 4; ++j) acc[wr][m][j] = (f32x4){0.f, 0.f, 0.f, 0.f};

    __syncthreads();  // drains DMA(0) + zero-writes + demod; xs ready

    for (int cc = 0; cc < 8; ++cc) {
#pragma unroll
        for (int dx = 0; dx < 3; ++dx) {
            // af window: only the dy-column of the stencil for this dx
            bf16x8 af[2][3];
#pragma unroll
            for (int m = 0; m < 2; ++m)
#pragma unroll
                for (int dy = 0; dy < 3; ++dy)
                    af[m][dy] = *(const bf16x8*)(
                        wb + (size_t)(m * 16 * 9 + dy * 3 + dx) * CIN + cc * 32);
#pragma unroll
            for (int r4 = 0; r4 < 4; ++r4) {
                int rr = rq * 2 + r4;  // LDS y-row 0..9
#pragma unroll
                for (int j = 0; j < 4; ++j) {
                    bf16x8 bv = *(const bf16x8*)(
                        &xs[((rr * 4 + quad) * 66 + j * 16 + n + dx) * 8]);
#pragma unroll
                    for (int wr = 0; wr < 2; ++wr) {
                        int dy = r4 - wr;   // compile-time after unroll
                        if (dy >= 0 && dy <= 2) {
                            acc[wr][0][j] = __builtin_amdgcn_mfma_f32_16x16x32_bf16(
                                af[0][dy], bv, acc[wr][0][j], 0, 0, 0);
                            acc[wr][1][j] = __builtin_amdgcn_mfma_f32_16x16x32_bf16(
                                af[1][dy], bv, acc[wr][1][j], 0, 0, 0);
                        }
                    }
                }
            }
        }
        __syncthreads();  // all waves done READING xs for chunk cc
        if (cc < 7) {
            stage_dma8(xs, xm, b, cc + 1, Y0, lane, wave);
            __syncthreads();  // vmcnt drained -> chunk cc+1 visible
        }
    }

    // epilogue: C/D layout col=lane&15 (px), row=quad*4+reg (co)
    const float ms = 1.0f / 48.0f;
#pragma unroll
    for (int wr = 0; wr < 2; ++wr) {
        int gy = Y0 + rq * 2 + wr;
#pragma unroll
        for (int m = 0; m < 2; ++m) {
            int cl = wco * 32 + m * 16 + quad * 4;
            int cobase = co0 + cl;
            float d0 = dls[cl + 0] * ms;
            float d1 = dls[cl + 1] * ms;
            float d2 = dls[cl + 2] * ms;
            float d3 = dls[cl + 3] * ms;
#pragma unroll
            for (int j = 0; j < 4; ++j) {
                int gx = j * 16 + n;
                size_t o = ((size_t)(b * COUT + cobase) * HH + gy) * WW + gx;
                out[o]                       = acc[wr][m][j][0] * d0;
                out[o + (size_t)HH * WW]     = acc[wr][m][j][1] * d1;
                out[o + (size_t)2 * HH * WW] = acc[wr][m][j][2] * d2;
                out[o + (size_t)3 * HH * WW] = acc[wr][m][j][3] * d3;
            }
        }
    }
}

// =================== fallback path (no xm workspace) ======================
__global__ void style_proj_kernel(const float* __restrict__ style,
                                  const float* __restrict__ style_w,
                                  const float* __restrict__ style_b,
                                  float* __restrict__ s) {
    __shared__ float red[3][64];
    int l    = threadIdx.x & 63;
    int part = threadIdx.x >> 6;
    int ci   = blockIdx.x * 64 + l;
    int b    = blockIdx.y;
    float acc = 0.f;
    const float* st = style + b * SDIM + part * (SDIM / 4);
    const float* W  = style_w + (size_t)(part * (SDIM / 4)) * CIN + ci;
#pragma unroll 4
    for (int k = 0; k < SDIM / 4; ++k) acc += st[k] * W[(size_t)k * CIN];
    if (part) red[part - 1][l] = acc;
    __syncthreads();
    if (part == 0)
        s[b * CIN + ci] = acc + red[0][l] + red[1][l] + red[2][l] + style_b[ci];
}

__global__ void demod_kernel(const float* __restrict__ wsq,
                             const float* __restrict__ s,
                             float* __restrict__ demod) {
    int b    = blockIdx.y;
    int co   = blockIdx.x * 4 + (threadIdx.x >> 6);
    int lane = threadIdx.x & 63;
    float acc = 0.f;
#pragma unroll
    for (int j = 0; j < CIN / 64; ++j) {
        int ci = j * 64 + lane;
        float sv = s[b * CIN + ci];
        acc += wsq[co * CIN + ci] * sv * sv;
    }
#pragma unroll
    for (int off = 32; off > 0; off >>= 1)
        acc += __shfl_down(acc, off, 64);
    if (lane == 0)
        demod[b * COUT + co] = rsqrtf(acc * (1.0f / (CIN * 9)) + 1e-8f);
}

__device__ __forceinline__ void stage_tile(
    __hip_bfloat16* __restrict__ xsb,
    const float* __restrict__ x, const float* __restrict__ s,
    int b, int cc, int Y0, int lane, int wave) {
#pragma unroll
    for (int i = 0; i < 6; ++i) {
        int u = wave * 6 + i;
        int r = u >> 2, quad = u & 3;
        int y = Y0 - 1 + r;
        bf16x8 wv = (bf16x8){0, 0, 0, 0, 0, 0, 0, 0};
        if ((unsigned)y < (unsigned)HH) {
            const float* base =
                x + (((size_t)(b * CIN + cc * 32 + quad * 8)) * HH + y) * WW + lane;
            const float4* sp = (const float4*)(s + b * CIN + cc * 32 + quad * 8);
            float4 s0 = sp[0], s1 = sp[1];
            float sv[8] = {s0.x, s0.y, s0.z, s0.w, s1.x, s1.y, s1.z, s1.w};
#pragma unroll
            for (int c = 0; c < 8; ++c)
                wv[c] = f2bf(base[(size_t)c * (HH * WW)] * sv[c]);
        }
        *(bf16x8*)(xsb + (((r * 4 + quad) * 66) + 1 + lane) * 8) = wv;
        if (lane < 2) {
            bf16x8 z = (bf16x8){0, 0, 0, 0, 0, 0, 0, 0};
            *(bf16x8*)(xsb + (((r * 4 + quad) * 66) + lane * 65) * 8) = z;
        }
    }
}

__global__ __launch_bounds__(256, 2) void conv_mfma_fb(
    const float* __restrict__ x, const __hip_bfloat16* __restrict__ wT,
    const float* __restrict__ s, const float* __restrict__ demod,
    float* __restrict__ out) {
    __shared__ __hip_bfloat16 xs[2][6 * 4 * 66 * 8];

    int tid  = threadIdx.x;
    int lane = tid & 63;
    int wave = tid >> 6;
    int wco  = wave >> 1;
    int rp   = wave & 1;
    int n    = lane & 15;
    int quad = lane >> 4;

    int Y0  = blockIdx.x * 4;
    int co0 = blockIdx.y * 64;
    int b   = blockIdx.z;

    f32x4 acc[2][2][4];
#pragma unroll
    for (int wr = 0; wr < 2; ++wr)
#pragma unroll
        for (int m = 0; m < 2; ++m)
#pragma unroll
            for (int j = 0; j < 4; ++j) acc[wr][m][j] = (f32x4){0.f, 0.f, 0.f, 0.f};

    const __hip_bfloat16* wb =
        wT + ((size_t)(co0 + wco * 32 + n) * 9) * CIN + quad * 8;

    stage_tile(xs[0], x, s, b, 0, Y0, lane, wave);
    __syncthreads();

    for (int cc = 0; cc < 8; ++cc) {
        int cur = cc & 1;
        if (cc < 7) stage_tile(xs[cur ^ 1], x, s, b, cc + 1, Y0, lane, wave);

        bf16x8 af[2][9];
#pragma unroll
        for (int k = 0; k < 9; ++k) {
            af[0][k] = *(const bf16x8*)(wb + ((size_t)k) * CIN + cc * 32);
            af[1][k] = *(const bf16x8*)(wb + ((size_t)(16 * 9 + k)) * CIN + cc * 32);
        }

        const __hip_bfloat16* xb = xs[cur];
#pragma unroll
        for (int r4 = 0; r4 < 4; ++r4) {
            int rr = rp * 2 + r4;
#pragma unroll
            for (int dx = 0; dx < 3; ++dx) {
#pragma unroll
                for (int j = 0; j < 4; ++j) {
                    bf16x8 bv = *(const bf16x8*)(
                        xb + (((rr * 4 + quad) * 66) + j * 16 + n + dx) * 8);
                    if (r4 <= 2) {
                        acc[0][0][j] = __builtin_amdgcn_mfma_f32_16x16x32_bf16(
                            af[0][r4 * 3 + dx], bv, acc[0][0][j], 0, 0, 0);
                        acc[0][1][j] = __builtin_amdgcn_mfma_f32_16x16x32_bf16(
                            af[1][r4 * 3 + dx], bv, acc[0][1][j], 0, 0, 0);
                    }
                    if (r4 >= 1) {
                        acc[1][0][j] = __builtin_amdgcn_mfma_f32_16x16x32_bf16(
                            af[0][(r4 - 1) * 3 + dx], bv, acc[1][0][j], 0, 0, 0);
                        acc[1][1][j] = __builtin_amdgcn_mfma_f32_16x16x32_bf16(
                            af[1][(r4 - 1) * 3 + dx], bv, acc[1][1][j], 0, 0, 0);
                    }
                }
            }
        }
        __syncthreads();
    }

    const float ms = 1.0f / 48.0f;
#pragma unroll
    for (int wr = 0; wr < 2; ++wr) {
        int gy = Y0 + rp * 2 + wr;
#pragma unroll
        for (int m = 0; m < 2; ++m) {
            int cobase = co0 + wco * 32 + m * 16 + quad * 4;
            float d0 = demod[b * COUT + cobase + 0] * ms;
            float d1 = demod[b * COUT + cobase + 1] * ms;
            float d2 = demod[b * COUT + cobase + 2] * ms;
            float d3 = demod[b * COUT + cobase + 3] * ms;
#pragma unroll
            for (int j = 0; j < 4; ++j) {
                int gx = j * 16 + n;
                size_t o = ((size_t)(b * COUT + cobase) * HH + gy) * WW + gx;
                out[o]                       = acc[wr][m][j][0] * d0;
                out[o + (size_t)HH * WW]     = acc[wr][m][j][1] * d1;
                out[o + (size_t)2 * HH * WW] = acc[wr][m][j][2] * d2;
                out[o + (size_t)3 * HH * WW] = acc[wr][m][j][3] * d3;
            }
        }
    }
}

extern "C" void kernel_launch(void* const* d_in, const int* in_sizes, int n_in,
                              void* d_out, int out_size, void* d_ws, size_t ws_size,
                              hipStream_t stream) {
    const float* x       = (const float*)d_in[0];  // [16,256,64,64]
    const float* style   = (const float*)d_in[1];  // [16,512]
    const float* weight  = (const float*)d_in[2];  // [256,256,3,3]
    const float* style_w = (const float*)d_in[3];  // [512,256]
    const float* style_b = (const float*)d_in[4];  // [256]
    float* out = (float*)d_out;

    // ws: s[4096]f | wsq[65536]f | demod[4096]f | wT[589824]bf16 | xm[16.8M]bf16
    float* s     = (float*)d_ws;
    float* wsq   = s + BB * CIN;
    float* demod = wsq + COUT * CIN;
    __hip_bfloat16* wT = (__hip_bfloat16*)(demod + BB * COUT);
    __hip_bfloat16* xm = wT + (size_t)COUT * 9 * CIN;

    size_t need = (size_t)(BB * CIN + COUT * CIN + BB * COUT) * sizeof(float) +
                  (size_t)COUT * 9 * CIN * sizeof(__hip_bfloat16) +
                  (size_t)BB * CIN * HH * WW * sizeof(__hip_bfloat16);

    wprep_kernel<<<COUT, CIN, 0, stream>>>(weight, wT, wsq);

    if (ws_size >= need) {
        xmod_kernel<<<dim3(HH / 4, CIN / 8, BB), 256, 0, stream>>>(
            x, style, style_w, style_b, s, xm);
        conv_mfma_kernel<<<dim3(HH / 8, COUT / 64, BB), 512, 0, stream>>>(
            xm, wT, wsq, s, out);
    } else {
        style_proj_kernel<<<dim3(CIN / 64, BB), 256, 0, stream>>>(
            style, style_w, style_b, s);
        demod_kernel<<<dim3(COUT / 4, BB), 256, 0, stream>>>(wsq, s, demod);
        conv_mfma_fb<<<dim3(HH / 4, COUT / 64, BB), 256, 0, stream>>>(
            x, wT, s, demod, out);
    }
}

// Round 7
// 200.335 us; speedup vs baseline: 1.4662x; 1.4662x over previous
//
#include <hip/hip_runtime.h>
#include <hip/hip_bf16.h>

#define BB 16
#define CIN 256
#define COUT 256
#define HH 64
#define WW 64
#define SDIM 512

typedef __attribute__((ext_vector_type(8))) short bf16x8;
typedef __attribute__((ext_vector_type(4))) float f32x4;

static __device__ __forceinline__ short f2bf(float v) {
    __hip_bfloat16 h = __float2bfloat16(v);
    return *reinterpret_cast<short*>(&h);
}

// ------- kernel 1: style projection + weight prep, merged dispatch -------
__global__ void prep_kernel(const float* __restrict__ style,
                            const float* __restrict__ style_w,
                            const float* __restrict__ style_b,
                            const float* __restrict__ weight,
                            float* __restrict__ s,
                            __hip_bfloat16* __restrict__ wT,
                            float* __restrict__ wsq) {
    __shared__ float red[3][64];
    int bx = blockIdx.x;
    if (bx < 64) {
        int l    = threadIdx.x & 63;
        int part = threadIdx.x >> 6;   // 4 parts x 128 sdim
        int ci   = (bx & 3) * 64 + l;
        int b    = bx >> 2;
        float acc = 0.f;
        const float* st = style + b * SDIM + part * (SDIM / 4);
        const float* W  = style_w + (size_t)(part * (SDIM / 4)) * CIN + ci;
#pragma unroll 4
        for (int k = 0; k < SDIM / 4; ++k) acc += st[k] * W[(size_t)k * CIN];
        if (part) red[part - 1][l] = acc;
        __syncthreads();
        if (part == 0)
            s[b * CIN + ci] =
                acc + red[0][l] + red[1][l] + red[2][l] + style_b[ci];
    } else {
        int co = bx - 64;      // 256
        int ci = threadIdx.x;  // 256
        const float* wp = weight + ((size_t)co * CIN + ci) * 9;
        float acc = 0.f;
#pragma unroll
        for (int k = 0; k < 9; ++k) {
            float v = wp[k];
            acc += v * v;
            wT[((size_t)co * 9 + k) * CIN + ci] = __float2bfloat16(v);
        }
        wsq[co * CIN + ci] = acc;
    }
}

// ---------------- kernel (fallback only): demod[b,co] ---------------------
__global__ void demod_kernel(const float* __restrict__ wsq,
                             const float* __restrict__ s,
                             float* __restrict__ demod) {
    int b    = blockIdx.y;
    int co   = blockIdx.x * 4 + (threadIdx.x >> 6);
    int lane = threadIdx.x & 63;
    float acc = 0.f;
#pragma unroll
    for (int j = 0; j < CIN / 64; ++j) {
        int ci = j * 64 + lane;
        float sv = s[b * CIN + ci];
        acc += wsq[co * CIN + ci] * sv * sv;
    }
#pragma unroll
    for (int off = 32; off > 0; off >>= 1)
        acc += __shfl_down(acc, off, 64);
    if (lane == 0)
        demod[b * COUT + co] = rsqrtf(acc * (1.0f / (CIN * 9)) + 1e-8f);
}

// ------- kernel 2: xmod = bf16(x * s), ci8-interleaved (UNPADDED) ---------
// layout xm[b][g=ci/8][y][x][ci%8]: per (b,g,y) a row is 64px x 8ci = 1KB.
__global__ void xmod_kernel(const float* __restrict__ x,
                            const float* __restrict__ s,
                            __hip_bfloat16* __restrict__ xm) {
    int px = threadIdx.x & 63;
    int y  = blockIdx.x * 4 + (threadIdx.x >> 6);
    int g  = blockIdx.y;
    int b  = blockIdx.z;
    const float* xp = x + (((size_t)(b * CIN + g * 8)) * HH + y) * WW + px;
    const float4* sp = (const float4*)(s + b * CIN + g * 8);
    float4 s0 = sp[0], s1 = sp[1];
    float sv[8] = {s0.x, s0.y, s0.z, s0.w, s1.x, s1.y, s1.z, s1.w};
    bf16x8 v;
#pragma unroll
    for (int c = 0; c < 8; ++c) v[c] = f2bf(xp[(size_t)c * (HH * WW)] * sv[c]);
    *(bf16x8*)(xm + ((((size_t)(b * 32 + g)) * HH + y) * WW + px) * 8) = v;
}

// ---- async global->LDS DMA for one ci-chunk: 9 insts/wave, 0 VALU regs ---
// 72 (y,g) units; LDS dest = uniform base (+HW lane*16B); src per-lane.
__device__ __forceinline__ void stage_dma(__hip_bfloat16* xsb,
                                          const __hip_bfloat16* __restrict__ xm,
                                          int b, int cc, int Y0, int lane,
                                          int wave) {
#pragma unroll
    for (int i = 0; i < 9; ++i) {
        int u = wave * 9 + i;          // u = y*4 + g, y in [0,18)
        int y = u >> 2, g = u & 3;
        int yr = Y0 - 1 + y;
        if ((unsigned)yr < (unsigned)HH) {   // wave-uniform branch
            __hip_bfloat16* dst = xsb + (u * 66 + 1) * 8;  // cols 1..64
            const __hip_bfloat16* src =
                xm + ((((size_t)(b * 32 + cc * 4 + g)) * HH + yr) * WW + lane) * 8;
            __builtin_amdgcn_global_load_lds(
                (const __attribute__((address_space(1))) void*)src,
                (__attribute__((address_space(3))) void*)dst, 16, 0, 0);
        }
    }
}

// ---- kernel 3: fused modulated conv, dbuf 2-phase, dx-outer af window ----
// R5 skeleton (97us proven): 16-row y-tile, 512 thr (8 waves = 2 co-halves x
// 4 row-quads), grid 256 = 1 block/CU, LDS dbuf 2x76032B, ONE barrier/cc,
// DMA prefetch hidden under compute.
// R7 change: af[2][9] (72 regs/cc) -> dx-outer af[2][3] (24 regs/phase).
// R5's regs were 124 arch + 128 acc ~= 252/256: ZERO headroom, so the
// compiler couldn't pipeline bv ds_reads ahead of MFMAs -> pipes serialized
// (MFMA 89k + LDS 74k + VALU 28k ~= measured 233k cyc/CU). Freeing ~48 regs
// lets ~10 bv loads stay in flight. DMA prefetch is issued at the START of
// the dx=2 phase: after that phase's af loads (af vmcnt-waits stay ahead of
// the DMA in the FIFO) and ~96 MFMAs before the barrier cover its latency.
// REVERT CRITERION: WRITE_SIZE >> 100MB = spill (R2 failure mode) -> R5.
__global__ __launch_bounds__(512, 2) void conv_mfma_kernel(
    const __hip_bfloat16* __restrict__ xm, const __hip_bfloat16* __restrict__ wT,
    const float* __restrict__ wsq, const float* __restrict__ s,
    float* __restrict__ out) {
    __shared__ __hip_bfloat16 xs[2][72 * 66 * 8];  // 2 x 76032 B
    __shared__ float dls[64];

    int tid  = threadIdx.x;
    int lane = tid & 63;
    int wave = tid >> 6;   // 0..7
    int wco  = wave & 1;   // co half (32 co)
    int rq   = wave >> 1;  // row quad: output rows rq*4 .. rq*4+3
    int n    = lane & 15;
    int quad = lane >> 4;

    int Y0  = blockIdx.x * 16;  // 4 spatial blocks x 16 output rows
    int co0 = blockIdx.y * 64;  // 4 co blocks
    int b   = blockIdx.z;

    const bf16x8 zv = (bf16x8){0, 0, 0, 0, 0, 0, 0, 0};
    // zero halo cols (0,65) of all 72 units, BOTH buffers — ONCE
    if (tid < 288) {
        int buf = tid / 144, idx = tid % 144;
        int u = idx >> 1, col = (idx & 1) * 65;
        *(bf16x8*)(&xs[buf][(u * 66 + col) * 8]) = zv;
    }
    // zero out-of-range rows — ONCE; DMA skips them forever
    if (Y0 == 0) {
        for (int c = tid; c < 528; c += 512) {   // units 0..3, cols 0..65, 2 bufs
            int buf = c / 264, idx = c % 264;
            *(bf16x8*)(&xs[buf][idx * 8]) = zv;
        }
    }
    if (Y0 + 16 == HH) {
        for (int c = tid; c < 528; c += 512) {   // units 68..71
            int buf = c / 264, idx = c % 264;
            *(bf16x8*)(&xs[buf][(68 * 66 + idx) * 8]) = zv;
        }
    }

    // issue first ci-chunk DMA ASAP; demod VALU below overlaps its latency
    stage_dma(xs[0], xm, b, 0, Y0, lane, wave);

    // inline demod for this block's 64 co (8 threads per co)
    {
        int colco = tid >> 3, part = tid & 7;
        float dacc = 0.f;
        const float* wrow = wsq + (size_t)(co0 + colco) * CIN + part * 32;
        const float* srow = s + b * CIN + part * 32;
#pragma unroll 8
        for (int i = 0; i < 32; ++i) {
            float sv = srow[i];
            dacc += wrow[i] * sv * sv;
        }
        dacc += __shfl_down(dacc, 4, 64);
        dacc += __shfl_down(dacc, 2, 64);
        dacc += __shfl_down(dacc, 1, 64);
        if (part == 0)
            dls[colco] = rsqrtf(dacc * (1.0f / (CIN * 9)) + 1e-8f);
    }

    // A base: wT[co][k][ci]; this wave's A rows: co0 + wco*32 + m*16 + n
    const __hip_bfloat16* wb =
        wT + ((size_t)(co0 + wco * 32 + n) * 9) * CIN + quad * 8;

    f32x4 acc[4][2][4];  // [wr][m][j] = 128 accumulator regs
#pragma unroll
    for (int wr = 0; wr < 4; ++wr)
#pragma unroll
        for (int m = 0; m < 2; ++m)
#pragma unroll
            for (int j = 0; j < 4; ++j) acc[wr][m][j] = (f32x4){0.f, 0.f, 0.f, 0.f};

    __syncthreads();  // drains DMA(0) + zero-writes + demod; xs[0] ready

    int cur = 0;
    for (int cc = 0; cc < 8; ++cc) {
        const __hip_bfloat16* xb = xs[cur];
#pragma unroll
        for (int dx = 0; dx < 3; ++dx) {
            // af window: only the dy-column of the stencil for this dx (24 regs)
            bf16x8 af[2][3];
#pragma unroll
            for (int m = 0; m < 2; ++m)
#pragma unroll
                for (int dy = 0; dy < 3; ++dy)
                    af[m][dy] = *(const bf16x8*)(
                        wb + (size_t)(m * 16 * 9 + dy * 3 + dx) * CIN + cc * 32);
            // prefetch next ci-chunk at the START of the LAST dx phase:
            // af(dx=2) loads sit ahead of the DMA in the vmcnt FIFO, and
            // the ~96 MFMAs below cover the DMA before the barrier drain.
            if (dx == 2 && cc < 7) stage_dma(xs[cur ^ 1], xm, b, cc + 1, Y0,
                                            lane, wave);
#pragma unroll
            for (int r6 = 0; r6 < 6; ++r6) {
                int rr = rq * 4 + r6;  // LDS y-row 0..17
#pragma unroll
                for (int j = 0; j < 4; ++j) {
                    bf16x8 bv = *(const bf16x8*)(
                        xb + ((rr * 4 + quad) * 66 + j * 16 + n + dx) * 8);
#pragma unroll
                    for (int wr = 0; wr < 4; ++wr) {
                        int dy = r6 - wr;   // compile-time after unroll
                        if (dy >= 0 && dy <= 2) {
                            acc[wr][0][j] = __builtin_amdgcn_mfma_f32_16x16x32_bf16(
                                af[0][dy], bv, acc[wr][0][j], 0, 0, 0);
                            acc[wr][1][j] = __builtin_amdgcn_mfma_f32_16x16x32_bf16(
                                af[1][dy], bv, acc[wr][1][j], 0, 0, 0);
                        }
                    }
                }
            }
        }
        __syncthreads();  // readers of xs[cur] done; DMA(cc+1) retired long ago
        cur ^= 1;
    }

    // epilogue: C/D layout col=lane&15 (px), row=quad*4+reg (co)
    const float ms = 1.0f / 48.0f;
#pragma unroll
    for (int wr = 0; wr < 4; ++wr) {
        int gy = Y0 + rq * 4 + wr;
#pragma unroll
        for (int m = 0; m < 2; ++m) {
            int cl = wco * 32 + m * 16 + quad * 4;
            int cobase = co0 + cl;
            float d0 = dls[cl + 0] * ms;
            float d1 = dls[cl + 1] * ms;
            float d2 = dls[cl + 2] * ms;
            float d3 = dls[cl + 3] * ms;
#pragma unroll
            for (int j = 0; j < 4; ++j) {
                int gx = j * 16 + n;
                size_t o = ((size_t)(b * COUT + cobase) * HH + gy) * WW + gx;
                out[o]                       = acc[wr][m][j][0] * d0;
                out[o + (size_t)HH * WW]     = acc[wr][m][j][1] * d1;
                out[o + (size_t)2 * HH * WW] = acc[wr][m][j][2] * d2;
                out[o + (size_t)3 * HH * WW] = acc[wr][m][j][3] * d3;
            }
        }
    }
}

// =================== fallback path (no xm workspace) ======================
__device__ __forceinline__ void stage_tile(
    __hip_bfloat16* __restrict__ xsb,
    const float* __restrict__ x, const float* __restrict__ s,
    int b, int cc, int Y0, int lane, int wave) {
#pragma unroll
    for (int i = 0; i < 6; ++i) {
        int u = wave * 6 + i;
        int r = u >> 2, quad = u & 3;
        int y = Y0 - 1 + r;
        bf16x8 wv = (bf16x8){0, 0, 0, 0, 0, 0, 0, 0};
        if ((unsigned)y < (unsigned)HH) {
            const float* base =
                x + (((size_t)(b * CIN + cc * 32 + quad * 8)) * HH + y) * WW + lane;
            const float4* sp = (const float4*)(s + b * CIN + cc * 32 + quad * 8);
            float4 s0 = sp[0], s1 = sp[1];
            float sv[8] = {s0.x, s0.y, s0.z, s0.w, s1.x, s1.y, s1.z, s1.w};
#pragma unroll
            for (int c = 0; c < 8; ++c)
                wv[c] = f2bf(base[(size_t)c * (HH * WW)] * sv[c]);
        }
        *(bf16x8*)(xsb + (((r * 4 + quad) * 66) + 1 + lane) * 8) = wv;
        if (lane < 2) {
            bf16x8 z = (bf16x8){0, 0, 0, 0, 0, 0, 0, 0};
            *(bf16x8*)(xsb + (((r * 4 + quad) * 66) + lane * 65) * 8) = z;
        }
    }
}

__global__ __launch_bounds__(256, 2) void conv_mfma_fb(
    const float* __restrict__ x, const __hip_bfloat16* __restrict__ wT,
    const float* __restrict__ s, const float* __restrict__ demod,
    float* __restrict__ out) {
    __shared__ __hip_bfloat16 xs[2][6 * 4 * 66 * 8];

    int tid  = threadIdx.x;
    int lane = tid & 63;
    int wave = tid >> 6;
    int wco  = wave >> 1;
    int rp   = wave & 1;
    int n    = lane & 15;
    int quad = lane >> 4;

    int Y0  = blockIdx.x * 4;
    int co0 = blockIdx.y * 64;
    int b   = blockIdx.z;

    f32x4 acc[2][2][4];
#pragma unroll
    for (int wr = 0; wr < 2; ++wr)
#pragma unroll
        for (int m = 0; m < 2; ++m)
#pragma unroll
            for (int j = 0; j < 4; ++j) acc[wr][m][j] = (f32x4){0.f, 0.f, 0.f, 0.f};

    const __hip_bfloat16* wb =
        wT + ((size_t)(co0 + wco * 32 + n) * 9) * CIN + quad * 8;

    stage_tile(xs[0], x, s, b, 0, Y0, lane, wave);
    __syncthreads();

    for (int cc = 0; cc < 8; ++cc) {
        int cur = cc & 1;
        if (cc < 7) stage_tile(xs[cur ^ 1], x, s, b, cc + 1, Y0, lane, wave);

        bf16x8 af[2][9];
#pragma unroll
        for (int k = 0; k < 9; ++k) {
            af[0][k] = *(const bf16x8*)(wb + ((size_t)k) * CIN + cc * 32);
            af[1][k] = *(const bf16x8*)(wb + ((size_t)(16 * 9 + k)) * CIN + cc * 32);
        }

        const __hip_bfloat16* xb = xs[cur];
#pragma unroll
        for (int r4 = 0; r4 < 4; ++r4) {
            int rr = rp * 2 + r4;
#pragma unroll
            for (int dx = 0; dx < 3; ++dx) {
#pragma unroll
                for (int j = 0; j < 4; ++j) {
                    bf16x8 bv = *(const bf16x8*)(
                        xb + (((rr * 4 + quad) * 66) + j * 16 + n + dx) * 8);
                    if (r4 <= 2) {
                        acc[0][0][j] = __builtin_amdgcn_mfma_f32_16x16x32_bf16(
                            af[0][r4 * 3 + dx], bv, acc[0][0][j], 0, 0, 0);
                        acc[0][1][j] = __builtin_amdgcn_mfma_f32_16x16x32_bf16(
                            af[1][r4 * 3 + dx], bv, acc[0][1][j], 0, 0, 0);
                    }
                    if (r4 >= 1) {
                        acc[1][0][j] = __builtin_amdgcn_mfma_f32_16x16x32_bf16(
                            af[0][(r4 - 1) * 3 + dx], bv, acc[1][0][j], 0, 0, 0);
                        acc[1][1][j] = __builtin_amdgcn_mfma_f32_16x16x32_bf16(
                            af[1][(r4 - 1) * 3 + dx], bv, acc[1][1][j], 0, 0, 0);
                    }
                }
            }
        }
        __syncthreads();
    }

    const float ms = 1.0f / 48.0f;
#pragma unroll
    for (int wr = 0; wr < 2; ++wr) {
        int gy = Y0 + rp * 2 + wr;
#pragma unroll
        for (int m = 0; m < 2; ++m) {
            int cobase = co0 + wco * 32 + m * 16 + quad * 4;
            float d0 = demod[b * COUT + cobase + 0] * ms;
            float d1 = demod[b * COUT + cobase + 1] * ms;
            float d2 = demod[b * COUT + cobase + 2] * ms;
            float d3 = demod[b * COUT + cobase + 3] * ms;
#pragma unroll
            for (int j = 0; j < 4; ++j) {
                int gx = j * 16 + n;
                size_t o = ((size_t)(b * COUT + cobase) * HH + gy) * WW + gx;
                out[o]                       = acc[wr][m][j][0] * d0;
                out[o + (size_t)HH * WW]     = acc[wr][m][j][1] * d1;
                out[o + (size_t)2 * HH * WW] = acc[wr][m][j][2] * d2;
                out[o + (size_t)3 * HH * WW] = acc[wr][m][j][3] * d3;
            }
        }
    }
}

extern "C" void kernel_launch(void* const* d_in, const int* in_sizes, int n_in,
                              void* d_out, int out_size, void* d_ws, size_t ws_size,
                              hipStream_t stream) {
    const float* x       = (const float*)d_in[0];  // [16,256,64,64]
    const float* style   = (const float*)d_in[1];  // [16,512]
    const float* weight  = (const float*)d_in[2];  // [256,256,3,3]
    const float* style_w = (const float*)d_in[3];  // [512,256]
    const float* style_b = (const float*)d_in[4];  // [256]
    float* out = (float*)d_out;

    // ws: s[4096]f | wsq[65536]f | demod[4096]f | wT[589824]bf16 | xm[16.8M]bf16
    float* s     = (float*)d_ws;
    float* wsq   = s + BB * CIN;
    float* demod = wsq + COUT * CIN;
    __hip_bfloat16* wT = (__hip_bfloat16*)(demod + BB * COUT);
    __hip_bfloat16* xm = wT + (size_t)COUT * 9 * CIN;

    size_t need = (size_t)(BB * CIN + COUT * CIN + BB * COUT) * sizeof(float) +
                  (size_t)COUT * 9 * CIN * sizeof(__hip_bfloat16) +
                  (size_t)BB * CIN * HH * WW * sizeof(__hip_bfloat16);

    prep_kernel<<<320, 256, 0, stream>>>(style, style_w, style_b, weight,
                                         s, wT, wsq);

    if (ws_size >= need) {
        xmod_kernel<<<dim3(HH / 4, CIN / 8, BB), 256, 0, stream>>>(x, s, xm);
        conv_mfma_kernel<<<dim3(HH / 16, COUT / 64, BB), 512, 0, stream>>>(
            xm, wT, wsq, s, out);
    } else {
        demod_kernel<<<dim3(COUT / 4, BB), 256, 0, stream>>>(wsq, s, demod);
        conv_mfma_fb<<<dim3(HH / 4, COUT / 64, BB), 256, 0, stream>>>(
            x, wT, s, demod, out);
    }
}